// Round 1
// baseline (464.908 us; speedup 1.0000x reference)
//
#include <hip/hip_runtime.h>

typedef __attribute__((ext_vector_type(8))) __bf16 b16x8;
typedef __attribute__((ext_vector_type(4))) float f32x4;
typedef __attribute__((ext_vector_type(8))) unsigned short u16x8;
typedef unsigned short u16;

#define MFMA16(a, b, c) __builtin_amdgcn_mfma_f32_16x16x32_bf16((a), (b), (c), 0, 0, 0)
// XOR swizzle: spread 16B slots across banks for row-major bf16 tiles w/ 256B row stride
#define SW(byteoff, row) ((byteoff) ^ (((row) & 7) << 4))

__device__ __forceinline__ u16 f2bf_bits(float f) {
  union { float f; unsigned u; } v; v.f = f;
  unsigned r = (v.u + 0x7FFFu + ((v.u >> 16) & 1u)) >> 16;
  return (u16)r;
}
__device__ __forceinline__ float sigmf(float x) { return 1.f / (1.f + __expf(-x)); }
__device__ __forceinline__ float tanh_f(float x) { return 1.f - 2.f / (__expf(2.f * x) + 1.f); }
__device__ __forceinline__ f32x4 fzero4() { f32x4 z; z[0]=0.f; z[1]=0.f; z[2]=0.f; z[3]=0.f; return z; }
__device__ __forceinline__ b16x8 bzero8() {
  b16x8 z;
  #pragma unroll
  for (int j = 0; j < 8; ++j) z[j] = (__bf16)0.f;
  return z;
}

// ---------------- prep: weights -> bf16 in workspace ----------------
__global__ __launch_bounds__(256) void prep_kernel(
    const float* __restrict__ W1, const float* __restrict__ W2,
    const float* __restrict__ Wih, const float* __restrict__ Whh,
    const float* __restrict__ Wp, const float* __restrict__ Wv,
    const float* __restrict__ bih, const float* __restrict__ bhh,
    u16* __restrict__ W1b, u16* __restrict__ W2b, u16* __restrict__ Wihb,
    u16* __restrict__ Whhb, u16* __restrict__ Whb, float* __restrict__ gbp)
{
  int i = blockIdx.x * 256 + threadIdx.x;   // grid 256*256 = 65536
  if (i < 8192) {                            // W1 padded (128 x 64), K 54->64
    int r = i >> 6, k = i & 63;
    W1b[i] = f2bf_bits(k < 54 ? W1[r * 54 + k] : 0.f);
  }
  if (i < 16384) W2b[i] = f2bf_bits(W2[i]);  // 128x128
  Wihb[i] = f2bf_bits(Wih[i]);               // 512x128
  Whhb[i] = f2bf_bits(Whh[i]);               // 512x128
  if (i < 2048) {                            // head: rows 0-5 Wp, 6 Wv, 7-15 zero (16x128)
    int r = i >> 7, k = i & 127;
    float v = (r < 6) ? Wp[r * 128 + k] : ((r == 6) ? Wv[k] : 0.f);
    Whb[i] = f2bf_bits(v);
  }
  if (i < 512) gbp[i] = bih[i] + bhh[i];
}

// ---------------- phase 1: X2 = relu(relu(obs@W1^T+b1)@W2^T+b2) as bf16 ----------------
__global__ __launch_bounds__(256) void mlp_kernel(
    const float* __restrict__ obs, const float* __restrict__ b1v, const float* __restrict__ b2v,
    const u16* __restrict__ W1b, const u16* __restrict__ W2b, u16* __restrict__ X2)
{
  __shared__ u16 x1t[64 * 128];
  __shared__ u16 x2t[64 * 128];
  const int tid = threadIdx.x;
  const int w   = tid >> 6;
  const int l   = tid & 63;
  const int col = l & 15;
  const int q   = l >> 4;
  const long m0 = (long)blockIdx.x * 64;   // 4096 blocks * 64 rows = 262144 = T*N

  // ---- X1 stage: A-fragments straight from obs (f32 -> bf16), K padded to 64
  b16x8 a0[2];
  {
    const float* orow = obs + (m0 + 16 * w + col) * 54;
    #pragma unroll
    for (int c = 0; c < 2; ++c) {
      #pragma unroll
      for (int p = 0; p < 4; ++p) {
        int k0 = 32 * c + 8 * q + 2 * p;
        float x0 = 0.f, x1 = 0.f;
        if (k0 < 54) { x0 = orow[k0]; x1 = orow[k0 + 1]; }   // 54 even: pair all-valid or all-pad
        a0[c][2 * p]     = (__bf16)x0;
        a0[c][2 * p + 1] = (__bf16)x1;
      }
    }
  }
  f32x4 acc[8];
  #pragma unroll
  for (int i = 0; i < 8; ++i) acc[i] = fzero4();
  #pragma unroll
  for (int nt = 0; nt < 8; ++nt) {
    #pragma unroll
    for (int c = 0; c < 2; ++c) {
      b16x8 b = *(const b16x8*)(W1b + (nt * 16 + col) * 64 + 8 * q + 32 * c);
      acc[nt] = MFMA16(a0[c], b, acc[nt]);
    }
  }
  #pragma unroll
  for (int nt = 0; nt < 8; ++nt) {
    float bb = b1v[nt * 16 + col];
    #pragma unroll
    for (int r = 0; r < 4; ++r) {
      float v = fmaxf(acc[nt][r] + bb, 0.f);
      int row = 16 * w + 4 * q + r;
      int byteoff = row * 256 + (nt * 16 + col) * 2;
      *(u16*)((char*)x1t + SW(byteoff, row)) = f2bf_bits(v);
    }
  }
  __syncthreads();

  // ---- X2 stage
  b16x8 a1[4];
  #pragma unroll
  for (int c = 0; c < 4; ++c) {
    int row = 16 * w + col;
    int byteoff = row * 256 + 16 * q + 64 * c;
    a1[c] = *(const b16x8*)((char*)x1t + SW(byteoff, row));
  }
  f32x4 acc2[8];
  #pragma unroll
  for (int i = 0; i < 8; ++i) acc2[i] = fzero4();
  #pragma unroll
  for (int nt = 0; nt < 8; ++nt) {
    #pragma unroll
    for (int c = 0; c < 4; ++c) {
      b16x8 b = *(const b16x8*)(W2b + (nt * 16 + col) * 128 + 8 * q + 32 * c);
      acc2[nt] = MFMA16(a1[c], b, acc2[nt]);
    }
  }
  #pragma unroll
  for (int nt = 0; nt < 8; ++nt) {
    float bb = b2v[nt * 16 + col];
    #pragma unroll
    for (int r = 0; r < 4; ++r) {
      float v = fmaxf(acc2[nt][r] + bb, 0.f);
      int row = 16 * w + 4 * q + r;
      int byteoff = row * 256 + (nt * 16 + col) * 2;
      *(u16*)((char*)x2t + SW(byteoff, row)) = f2bf_bits(v);
    }
  }
  __syncthreads();

  // ---- coalesced copy-out (unswizzle on read)
  #pragma unroll
  for (int i = 0; i < 4; ++i) {
    int e = tid + 256 * i;           // 16B chunk index, 1024 total
    int byteoff = e * 16;
    int row = byteoff >> 8;
    uint4 v = *(const uint4*)((char*)x2t + SW(byteoff, row));
    *(uint4*)((char*)X2 + m0 * 256 + byteoff) = v;
  }
}

// ---------------- phase 2: LSTM recurrence + fused heads ----------------
__global__ __launch_bounds__(256, 1) void lstm_kernel(
    const u16* __restrict__ X2, const float* __restrict__ h0, const float* __restrict__ c0,
    const int* __restrict__ done,
    const u16* __restrict__ Wihb, const u16* __restrict__ Whhb, const u16* __restrict__ Whb,
    const float* __restrict__ gb, const float* __restrict__ bp, const float* __restrict__ bv,
    float* __restrict__ out)
{
  __shared__ u16 hlds[16 * 128];
  const int tid = threadIdx.x;
  const int w   = tid >> 6;
  const int l   = tid & 63;
  const int col = l & 15;
  const int q   = l >> 4;
  const int n0  = blockIdx.x * 16;   // 128 blocks * 16 rows = 2048

  // wave w owns gate columns [32w,32w+32) of each of i,f,g,o:
  int tiles[8];
  #pragma unroll
  for (int g = 0; g < 4; ++g) { tiles[2 * g] = 2 * w + 8 * g; tiles[2 * g + 1] = 2 * w + 8 * g + 1; }

  // resident weight fragments (~256 VGPRs)
  b16x8 wih[8][4], whh[8][4];
  #pragma unroll
  for (int i = 0; i < 8; ++i) {
    int nt = tiles[i];
    #pragma unroll
    for (int c = 0; c < 4; ++c) {
      wih[i][c] = *(const b16x8*)(Wihb + (nt * 16 + col) * 128 + 8 * q + 32 * c);
      whh[i][c] = *(const b16x8*)(Whhb + (nt * 16 + col) * 128 + 8 * q + 32 * c);
    }
  }
  float gbr[8];
  #pragma unroll
  for (int i = 0; i < 8; ++i) gbr[i] = gb[tiles[i] * 16 + col];
  float hb = (col < 6) ? bp[col] : ((col == 6) ? bv[0] : 0.f);

  // c state in registers: rows 4q+r, k = 32w+16s+col
  float cc[4][2];
  #pragma unroll
  for (int r = 0; r < 4; ++r)
    #pragma unroll
    for (int s = 0; s < 2; ++s)
      cc[r][s] = c0[(n0 + 4 * q + r) * 128 + 32 * w + 16 * s + col];

  // h0 -> hlds (bf16, swizzled)
  {
    int e0 = tid * 8;
    int row = e0 >> 7;
    int k0 = e0 & 127;
    const float* hp = h0 + (n0 + row) * 128 + k0;
    u16x8 t8;
    #pragma unroll
    for (int j = 0; j < 8; ++j) t8[j] = f2bf_bits(hp[j]);
    int byteoff = row * 256 + k0 * 2;
    *(u16x8*)((char*)hlds + SW(byteoff, row)) = t8;
  }
  __syncthreads();

  // prefetch x2 fragments for t=0
  b16x8 xa[4];
  #pragma unroll
  for (int c = 0; c < 4; ++c)
    xa[c] = *(const b16x8*)(X2 + ((long)(n0 + col)) * 128 + 8 * q + 32 * c);

  float hval[4][2];

  for (int t = 0; t < 128; ++t) {
    int dA = 0, dcs[4] = {0, 0, 0, 0};
    if (t > 0) {
      const int* dr = done + (t - 1) * 2048 + n0;
      dA = dr[col];
      #pragma unroll
      for (int r = 0; r < 4; ++r) dcs[r] = dr[4 * q + r];
    }
    b16x8 ha[4];
    #pragma unroll
    for (int c = 0; c < 4; ++c) {
      int byteoff = col * 256 + 16 * q + 64 * c;
      ha[c] = *(const b16x8*)((char*)hlds + SW(byteoff, col));
      if (dA) ha[c] = bzero8();
    }
    #pragma unroll
    for (int r = 0; r < 4; ++r)
      if (dcs[r]) { cc[r][0] = 0.f; cc[r][1] = 0.f; }

    f32x4 acc[8];
    #pragma unroll
    for (int i = 0; i < 8; ++i) acc[i] = fzero4();
    #pragma unroll
    for (int i = 0; i < 8; ++i)
      #pragma unroll
      for (int c = 0; c < 4; ++c)
        acc[i] = MFMA16(xa[c], wih[i][c], acc[i]);
    #pragma unroll
    for (int i = 0; i < 8; ++i)
      #pragma unroll
      for (int c = 0; c < 4; ++c)
        acc[i] = MFMA16(ha[c], whh[i][c], acc[i]);

    int tn = (t < 127) ? (t + 1) : 127;
    b16x8 xan[4];
    #pragma unroll
    for (int c = 0; c < 4; ++c)
      xan[c] = *(const b16x8*)(X2 + ((long)tn * 2048 + n0 + col) * 128 + 8 * q + 32 * c);

    #pragma unroll
    for (int r = 0; r < 4; ++r) {
      #pragma unroll
      for (int s = 0; s < 2; ++s) {
        float gi = acc[0 + s][r] + gbr[0 + s];
        float gf = acc[2 + s][r] + gbr[2 + s];
        float gg = acc[4 + s][r] + gbr[4 + s];
        float go = acc[6 + s][r] + gbr[6 + s];
        float cn = sigmf(gf) * cc[r][s] + sigmf(gi) * tanh_f(gg);
        cc[r][s] = cn;
        hval[r][s] = sigmf(go) * tanh_f(cn);
      }
    }
    __syncthreads();   // everyone done reading h_{t-1}
    #pragma unroll
    for (int r = 0; r < 4; ++r) {
      #pragma unroll
      for (int s = 0; s < 2; ++s) {
        int row = 4 * q + r;
        int k = 32 * w + 16 * s + col;
        int byteoff = row * 256 + k * 2;
        *(u16*)((char*)hlds + SW(byteoff, row)) = f2bf_bits(hval[r][s]);
      }
    }
    __syncthreads();   // h_t visible

    if (w == 0) {      // heads: logits cols 0-5, value col 6
      b16x8 hh[4], wh[4];
      #pragma unroll
      for (int c = 0; c < 4; ++c) {
        int byteoff = col * 256 + 16 * q + 64 * c;
        hh[c] = *(const b16x8*)((char*)hlds + SW(byteoff, col));
        wh[c] = *(const b16x8*)(Whb + col * 128 + 8 * q + 32 * c);
      }
      f32x4 hacc = fzero4();
      #pragma unroll
      for (int c = 0; c < 4; ++c) hacc = MFMA16(hh[c], wh[c], hacc);
      #pragma unroll
      for (int r = 0; r < 4; ++r) {
        int n = n0 + 4 * q + r;
        float v = hacc[r] + hb;
        if (col < 6)       out[((long)t * 2048 + n) * 6 + col] = v;
        else if (col == 6) out[1572864 + (long)t * 2048 + n] = v;
      }
    }
    #pragma unroll
    for (int c = 0; c < 4; ++c) xa[c] = xan[c];
  }

  #pragma unroll
  for (int r = 0; r < 4; ++r) {
    #pragma unroll
    for (int s = 0; s < 2; ++s) {
      int row = 4 * q + r;
      int k = 32 * w + 16 * s + col;
      out[1835008 + (n0 + row) * 128 + k] = hval[r][s];
      out[2097152 + (n0 + row) * 128 + k] = cc[r][s];
    }
  }
}

extern "C" void kernel_launch(void* const* d_in, const int* in_sizes, int n_in,
                              void* d_out, int out_size, void* d_ws, size_t ws_size,
                              hipStream_t stream) {
  const float* obs  = (const float*)d_in[0];
  const float* h0   = (const float*)d_in[1];
  const float* c0   = (const float*)d_in[2];
  const int*   done = (const int*)d_in[3];
  const float* W1   = (const float*)d_in[4];
  const float* b1   = (const float*)d_in[5];
  const float* W2   = (const float*)d_in[6];
  const float* b2   = (const float*)d_in[7];
  const float* Wih  = (const float*)d_in[8];
  const float* Whh  = (const float*)d_in[9];
  const float* bih  = (const float*)d_in[10];
  const float* bhh  = (const float*)d_in[11];
  const float* Wp   = (const float*)d_in[12];
  const float* bp   = (const float*)d_in[13];
  const float* Wv   = (const float*)d_in[14];
  const float* bv   = (const float*)d_in[15];

  char* ws = (char*)d_ws;
  u16*   X2   = (u16*)(ws);                                      // 67108864 B
  u16*   W1b  = (u16*)(ws + 67108864);                           // 16384 B
  u16*   W2b  = (u16*)(ws + 67108864 + 16384);                   // 32768 B
  u16*   Wihb = (u16*)(ws + 67108864 + 16384 + 32768);           // 131072 B
  u16*   Whhb = (u16*)(ws + 67108864 + 16384 + 32768 + 131072);  // 131072 B
  u16*   Whb  = (u16*)(ws + 67108864 + 16384 + 32768 + 262144);  // 4096 B
  float* gbp  = (float*)(ws + 67108864 + 16384 + 32768 + 262144 + 4096);
  float* out  = (float*)d_out;

  hipLaunchKernelGGL(prep_kernel, dim3(256), dim3(256), 0, stream,
                     W1, W2, Wih, Whh, Wp, Wv, bih, bhh, W1b, W2b, Wihb, Whhb, Whb, gbp);
  hipLaunchKernelGGL(mlp_kernel, dim3(4096), dim3(256), 0, stream,
                     obs, b1, b2, W1b, W2b, X2);
  hipLaunchKernelGGL(lstm_kernel, dim3(128), dim3(256), 0, stream,
                     X2, h0, c0, done, Wihb, Whhb, Whb, gbp, bp, bv, out);
}

// Round 2
// 314.048 us; speedup vs baseline: 1.4804x; 1.4804x over previous
//
#include <hip/hip_runtime.h>

typedef __attribute__((ext_vector_type(8))) __bf16 b16x8;
typedef __attribute__((ext_vector_type(4))) float f32x4;
typedef unsigned short u16;

#define MFMA16(a, b, c) __builtin_amdgcn_mfma_f32_16x16x32_bf16((a), (b), (c), 0, 0, 0)
// XOR swizzle: spread 16B slots across banks for row-major bf16 tiles w/ 256B row stride
#define SW(byteoff, row) ((byteoff) ^ (((row) & 7) << 4))

__device__ __forceinline__ u16 f2bf_bits(float f) {
  union { float f; unsigned u; } v; v.f = f;
  unsigned r = (v.u + 0x7FFFu + ((v.u >> 16) & 1u)) >> 16;
  return (u16)r;
}
// raw transcendentals: v_rcp_f32 / v_exp_f32 (2^x) — avoids full-precision div sequence
__device__ __forceinline__ float rcp_f(float x) { float r; asm("v_rcp_f32 %0, %1" : "=v"(r) : "v"(x)); return r; }
__device__ __forceinline__ float exp2_f(float x) { float r; asm("v_exp_f32 %0, %1" : "=v"(r) : "v"(x)); return r; }
__device__ __forceinline__ float sigf(float x)   { return rcp_f(1.f + exp2_f(-1.442695040889f * x)); }
__device__ __forceinline__ float tanhf_(float x) { return 1.f - 2.f * rcp_f(1.f + exp2_f(2.885390081777f * x)); }

__device__ __forceinline__ f32x4 fzero4() { f32x4 z; z[0]=0.f; z[1]=0.f; z[2]=0.f; z[3]=0.f; return z; }
__device__ __forceinline__ b16x8 bzero8() {
  b16x8 z;
  #pragma unroll
  for (int j = 0; j < 8; ++j) z[j] = (__bf16)0.f;
  return z;
}

// ---------------- prep: weights -> bf16 in workspace ----------------
__global__ __launch_bounds__(256) void prep_kernel(
    const float* __restrict__ W1, const float* __restrict__ W2,
    const float* __restrict__ Wih, const float* __restrict__ Whh,
    const float* __restrict__ Wp, const float* __restrict__ Wv,
    const float* __restrict__ bih, const float* __restrict__ bhh,
    u16* __restrict__ W1b, u16* __restrict__ W2b, u16* __restrict__ Wihb,
    u16* __restrict__ Whhb, u16* __restrict__ Whb, float* __restrict__ gbp)
{
  int i = blockIdx.x * 256 + threadIdx.x;   // grid 256*256 = 65536
  if (i < 8192) {                            // W1 padded (128 x 64), K 54->64
    int r = i >> 6, k = i & 63;
    W1b[i] = f2bf_bits(k < 54 ? W1[r * 54 + k] : 0.f);
  }
  if (i < 16384) W2b[i] = f2bf_bits(W2[i]);  // 128x128
  Wihb[i] = f2bf_bits(Wih[i]);               // 512x128
  Whhb[i] = f2bf_bits(Whh[i]);               // 512x128
  if (i < 2048) {                            // head: rows 0-5 Wp, 6 Wv, 7-15 zero (16x128)
    int r = i >> 7, k = i & 127;
    float v = (r < 6) ? Wp[r * 128 + k] : ((r == 6) ? Wv[k] : 0.f);
    Whb[i] = f2bf_bits(v);
  }
  if (i < 512) gbp[i] = bih[i] + bhh[i];
}

// ---------------- phase 1: X2 = relu(relu(obs@W1^T+b1)@W2^T+b2) as bf16 ----------------
__global__ __launch_bounds__(256) void mlp_kernel(
    const float* __restrict__ obs, const float* __restrict__ b1v, const float* __restrict__ b2v,
    const u16* __restrict__ W1b, const u16* __restrict__ W2b, u16* __restrict__ X2)
{
  __shared__ __align__(16) float obst[64 * 54];
  __shared__ u16 x1t[64 * 128];
  __shared__ u16 x2t[64 * 128];
  const int tid = threadIdx.x;
  const int w   = tid >> 6;
  const int l   = tid & 63;
  const int col = l & 15;
  const int q   = l >> 4;
  const long m0 = (long)blockIdx.x * 64;   // 4096 blocks * 64 rows = 262144 = T*N

  // stage obs tile coalesced (64 rows x 54 f32 = 864 float4)
  {
    const float* osrc = obs + m0 * 54;
    #pragma unroll
    for (int j = 0; j < 4; ++j) {
      int i4 = tid + 256 * j;
      if (i4 < 864) *(float4*)&obst[i4 * 4] = *(const float4*)&osrc[i4 * 4];
    }
  }
  __syncthreads();

  // ---- X1 stage: A-fragments from obst, K padded to 64
  b16x8 a0[2];
  {
    const float* orow = obst + (16 * w + col) * 54;
    #pragma unroll
    for (int c = 0; c < 2; ++c) {
      #pragma unroll
      for (int p = 0; p < 4; ++p) {
        int k0 = 32 * c + 8 * q + 2 * p;
        float x0 = 0.f, x1 = 0.f;
        if (k0 < 54) { x0 = orow[k0]; x1 = orow[k0 + 1]; }   // 54 even: pair all-valid or all-pad
        a0[c][2 * p]     = (__bf16)x0;
        a0[c][2 * p + 1] = (__bf16)x1;
      }
    }
  }
  f32x4 acc[8];
  #pragma unroll
  for (int i = 0; i < 8; ++i) acc[i] = fzero4();
  #pragma unroll
  for (int nt = 0; nt < 8; ++nt) {
    #pragma unroll
    for (int c = 0; c < 2; ++c) {
      b16x8 b = *(const b16x8*)(W1b + (nt * 16 + col) * 64 + 8 * q + 32 * c);
      acc[nt] = MFMA16(a0[c], b, acc[nt]);
    }
  }
  #pragma unroll
  for (int nt = 0; nt < 8; ++nt) {
    float bb = b1v[nt * 16 + col];
    #pragma unroll
    for (int r = 0; r < 4; ++r) {
      float v = fmaxf(acc[nt][r] + bb, 0.f);
      int row = 16 * w + 4 * q + r;
      int byteoff = row * 256 + (nt * 16 + col) * 2;
      *(u16*)((char*)x1t + SW(byteoff, row)) = f2bf_bits(v);
    }
  }
  __syncthreads();

  // ---- X2 stage
  b16x8 a1[4];
  #pragma unroll
  for (int c = 0; c < 4; ++c) {
    int row = 16 * w + col;
    int byteoff = row * 256 + 16 * q + 64 * c;
    a1[c] = *(const b16x8*)((char*)x1t + SW(byteoff, row));
  }
  f32x4 acc2[8];
  #pragma unroll
  for (int i = 0; i < 8; ++i) acc2[i] = fzero4();
  #pragma unroll
  for (int nt = 0; nt < 8; ++nt) {
    #pragma unroll
    for (int c = 0; c < 4; ++c) {
      b16x8 b = *(const b16x8*)(W2b + (nt * 16 + col) * 128 + 8 * q + 32 * c);
      acc2[nt] = MFMA16(a1[c], b, acc2[nt]);
    }
  }
  #pragma unroll
  for (int nt = 0; nt < 8; ++nt) {
    float bb = b2v[nt * 16 + col];
    #pragma unroll
    for (int r = 0; r < 4; ++r) {
      float v = fmaxf(acc2[nt][r] + bb, 0.f);
      int row = 16 * w + 4 * q + r;
      int byteoff = row * 256 + (nt * 16 + col) * 2;
      *(u16*)((char*)x2t + SW(byteoff, row)) = f2bf_bits(v);
    }
  }
  __syncthreads();

  // ---- coalesced copy-out (unswizzle on read)
  #pragma unroll
  for (int i = 0; i < 4; ++i) {
    int e = tid + 256 * i;           // 16B chunk index, 1024 total
    int byteoff = e * 16;
    int row = byteoff >> 8;
    uint4 v = *(const uint4*)((char*)x2t + SW(byteoff, row));
    *(uint4*)((char*)X2 + m0 * 256 + byteoff) = v;
  }
}

// ---------------- phase 2: LSTM recurrence (h stored in-place over X2) ----------------
// 256 blocks x 8 batch rows, 512 threads (8 waves); wave w owns gate cols [16w,16w+16)
__global__ __launch_bounds__(512) void lstm_kernel(
    u16* __restrict__ X2,   // in: x2 projections; out: H (bf16 h_t), written in place
    const float* __restrict__ h0, const float* __restrict__ c0,
    const int* __restrict__ done,
    const u16* __restrict__ Wihb, const u16* __restrict__ Whhb,
    const float* __restrict__ gb, float* __restrict__ out)
{
  __shared__ u16 hbuf[2][8 * 128];   // ping-pong h tile (swizzled)
  __shared__ int dsh[1024];          // done[t][0..7] staged
  const int tid = threadIdx.x;
  const int w   = tid >> 6;
  const int l   = tid & 63;
  const int col = l & 15;
  const int q   = l >> 4;
  const int cl  = col & 7;           // clamp to own 8 rows (rows 8..15 of M-tile unused)
  const int n0  = blockIdx.x * 8;    // 256 blocks * 8 rows = 2048
  const bool act = (q < 2);          // lanes holding valid output rows (0..7)

  // resident weight fragments: 4 gate-tiles (nt = 8g + w), K=128 (4 slots)
  b16x8 wih[4][4], whh[4][4];
  #pragma unroll
  for (int g = 0; g < 4; ++g) {
    int nt = 8 * g + w;
    #pragma unroll
    for (int c = 0; c < 4; ++c) {
      wih[g][c] = *(const b16x8*)(Wihb + (nt * 16 + col) * 128 + 8 * q + 32 * c);
      whh[g][c] = *(const b16x8*)(Whhb + (nt * 16 + col) * 128 + 8 * q + 32 * c);
    }
  }
  float gbr[4];
  #pragma unroll
  for (int g = 0; g < 4; ++g) gbr[g] = gb[(8 * g + w) * 16 + col];

  // c-state in registers (valid for act lanes): row 4q+r, hcol 16w+col
  float cc[4];
  #pragma unroll
  for (int r = 0; r < 4; ++r)
    cc[r] = act ? c0[(n0 + 4 * q + r) * 128 + 16 * w + col] : 0.f;

  // stage h0 -> hbuf[0] (bf16, swizzled); stage done -> dsh
  #pragma unroll
  for (int j = 0; j < 2; ++j) {
    int idx = tid * 2 + j;           // 1024 = 8 rows * 128
    int row = idx >> 7, k = idx & 127;
    *(u16*)((char*)hbuf[0] + SW(row * 256 + k * 2, row)) = f2bf_bits(h0[(n0 + row) * 128 + k]);
    dsh[idx] = done[(idx >> 3) * 2048 + n0 + (idx & 7)];
  }
  __syncthreads();

  // prefetch x2 fragments for t=0
  b16x8 xa[4];
  #pragma unroll
  for (int c = 0; c < 4; ++c)
    xa[c] = *(const b16x8*)(X2 + ((long)(n0 + cl)) * 128 + 8 * q + 32 * c);

  int dA = 0, dC[4] = {0, 0, 0, 0};
  float hval[4];

  for (int t = 0; t < 128; ++t) {
    const int cur = t & 1;

    b16x8 ha[4];
    #pragma unroll
    for (int c = 0; c < 4; ++c) {
      ha[c] = *(const b16x8*)((char*)hbuf[cur] + SW(cl * 256 + 16 * q + 64 * c, cl));
      if (dA) ha[c] = bzero8();
    }
    #pragma unroll
    for (int r = 0; r < 4; ++r)
      if (dC[r]) cc[r] = 0.f;

    f32x4 acc[4];
    #pragma unroll
    for (int g = 0; g < 4; ++g) acc[g] = fzero4();
    #pragma unroll
    for (int g = 0; g < 4; ++g)
      #pragma unroll
      for (int c = 0; c < 4; ++c)
        acc[g] = MFMA16(xa[c], wih[g][c], acc[g]);
    #pragma unroll
    for (int g = 0; g < 4; ++g)
      #pragma unroll
      for (int c = 0; c < 4; ++c)
        acc[g] = MFMA16(ha[c], whh[g][c], acc[g]);

    // prefetch next step's x2 fragments + done masks (off critical path)
    b16x8 xan[4];
    if (t < 127) {
      #pragma unroll
      for (int c = 0; c < 4; ++c)
        xan[c] = *(const b16x8*)(X2 + ((long)(t + 1) * 2048 + n0 + cl) * 128 + 8 * q + 32 * c);
      dA = dsh[t * 8 + cl];
      #pragma unroll
      for (int r = 0; r < 4; ++r) dC[r] = dsh[t * 8 + ((4 * q + r) & 7)];
    }

    // elementwise LSTM cell (i,f,g,o)
    #pragma unroll
    for (int r = 0; r < 4; ++r) {
      float gi = acc[0][r] + gbr[0];
      float gf = acc[1][r] + gbr[1];
      float gg = acc[2][r] + gbr[2];
      float go = acc[3][r] + gbr[3];
      float cn = sigf(gf) * cc[r] + sigf(gi) * tanhf_(gg);
      cc[r] = cn;
      hval[r] = sigf(go) * tanhf_(cn);
    }

    // write h_t to the other LDS buffer (swizzled)
    if (act) {
      #pragma unroll
      for (int r = 0; r < 4; ++r) {
        int row = 4 * q + r, k = 16 * w + col;
        *(u16*)((char*)hbuf[cur ^ 1] + SW(row * 256 + k * 2, row)) = f2bf_bits(hval[r]);
      }
    }
    __syncthreads();   // h_t visible; next iter reads hbuf[cur^1]

    // store H[t] over the (consumed) X2[t] region — drains at next barrier
    if (act) {
      #pragma unroll
      for (int r = 0; r < 4; ++r) {
        int row = 4 * q + r, k = 16 * w + col;
        X2[((long)t * 2048 + n0 + row) * 128 + k] = f2bf_bits(hval[r]);
      }
    }
    if (t < 127) {
      #pragma unroll
      for (int c = 0; c < 4; ++c) xa[c] = xan[c];
    }
  }

  // final hT / cT (f32)
  if (act) {
    #pragma unroll
    for (int r = 0; r < 4; ++r) {
      int row = 4 * q + r, k = 16 * w + col;
      out[1835008 + (n0 + row) * 128 + k] = hval[r];
      out[2097152 + (n0 + row) * 128 + k] = cc[r];
    }
  }
}

// ---------------- phase 3: heads (logits + value) from H, fully parallel ----------------
__global__ __launch_bounds__(256) void head_kernel(
    const u16* __restrict__ H, const u16* __restrict__ Whb,
    const float* __restrict__ bp, const float* __restrict__ bv, float* __restrict__ out)
{
  const int tid = threadIdx.x;
  const int w   = tid >> 6;
  const int l   = tid & 63;
  const int col = l & 15;
  const int q   = l >> 4;
  const long m0 = (long)blockIdx.x * 64;   // 4096 blocks * 64 rows

  b16x8 a[4], b[4];
  #pragma unroll
  for (int c = 0; c < 4; ++c) {
    a[c] = *(const b16x8*)(H + (m0 + 16 * w + col) * 128 + 8 * q + 32 * c);
    b[c] = *(const b16x8*)(Whb + col * 128 + 8 * q + 32 * c);
  }
  f32x4 acc = fzero4();
  #pragma unroll
  for (int c = 0; c < 4; ++c) acc = MFMA16(a[c], b[c], acc);
  float hb = (col < 6) ? bp[col] : ((col == 6) ? bv[0] : 0.f);
  #pragma unroll
  for (int r = 0; r < 4; ++r) {
    long m = m0 + 16 * w + 4 * q + r;    // global row index = t*2048+n
    float v = acc[r] + hb;
    if (col < 6)       out[m * 6 + col] = v;
    else if (col == 6) out[1572864 + m] = v;
  }
}

extern "C" void kernel_launch(void* const* d_in, const int* in_sizes, int n_in,
                              void* d_out, int out_size, void* d_ws, size_t ws_size,
                              hipStream_t stream) {
  const float* obs  = (const float*)d_in[0];
  const float* h0   = (const float*)d_in[1];
  const float* c0   = (const float*)d_in[2];
  const int*   done = (const int*)d_in[3];
  const float* W1   = (const float*)d_in[4];
  const float* b1   = (const float*)d_in[5];
  const float* W2   = (const float*)d_in[6];
  const float* b2   = (const float*)d_in[7];
  const float* Wih  = (const float*)d_in[8];
  const float* Whh  = (const float*)d_in[9];
  const float* bih  = (const float*)d_in[10];
  const float* bhh  = (const float*)d_in[11];
  const float* Wp   = (const float*)d_in[12];
  const float* bp   = (const float*)d_in[13];
  const float* Wv   = (const float*)d_in[14];
  const float* bv   = (const float*)d_in[15];

  char* ws = (char*)d_ws;
  u16*   X2   = (u16*)(ws);                                      // 67108864 B (X2, then H in place)
  u16*   W1b  = (u16*)(ws + 67108864);                           // 16384 B
  u16*   W2b  = (u16*)(ws + 67108864 + 16384);                   // 32768 B
  u16*   Wihb = (u16*)(ws + 67108864 + 16384 + 32768);           // 131072 B
  u16*   Whhb = (u16*)(ws + 67108864 + 16384 + 32768 + 131072);  // 131072 B
  u16*   Whb  = (u16*)(ws + 67108864 + 16384 + 32768 + 262144);  // 4096 B
  float* gbp  = (float*)(ws + 67108864 + 16384 + 32768 + 262144 + 4096);
  float* out  = (float*)d_out;

  hipLaunchKernelGGL(prep_kernel, dim3(256), dim3(256), 0, stream,
                     W1, W2, Wih, Whh, Wp, Wv, bih, bhh, W1b, W2b, Wihb, Whhb, Whb, gbp);
  hipLaunchKernelGGL(mlp_kernel, dim3(4096), dim3(256), 0, stream,
                     obs, b1, b2, W1b, W2b, X2);
  hipLaunchKernelGGL(lstm_kernel, dim3(256), dim3(512), 0, stream,
                     X2, h0, c0, done, Wihb, Whhb, gbp, out);
  hipLaunchKernelGGL(head_kernel, dim3(4096), dim3(256), 0, stream,
                     X2, Whb, bp, bv, out);
}

// Round 3
// 297.377 us; speedup vs baseline: 1.5634x; 1.0561x over previous
//
#include <hip/hip_runtime.h>

typedef __attribute__((ext_vector_type(8))) __bf16 b16x8;
typedef __attribute__((ext_vector_type(4))) float f32x4;
typedef __attribute__((ext_vector_type(8))) unsigned short u16x8;
typedef unsigned short u16;
typedef unsigned int u32;

#define MFMA16(a, b, c) __builtin_amdgcn_mfma_f32_16x16x32_bf16((a), (b), (c), 0, 0, 0)
// XOR swizzle: spread 16B slots across banks for row-major bf16 tiles w/ 256B row stride
#define SW(byteoff, row) ((byteoff) ^ (((row) & 7) << 4))
#define LOG2E 1.4426950408889634f

__device__ __forceinline__ u16 f2bf_bits(float f) {
  union { float f; unsigned u; } v; v.f = f;
  unsigned r = (v.u + 0x7FFFu + ((v.u >> 16) & 1u)) >> 16;
  return (u16)r;
}
__device__ __forceinline__ float rcp_f(float x) { float r; asm("v_rcp_f32 %0, %1" : "=v"(r) : "v"(x)); return r; }
__device__ __forceinline__ float exp2_f(float x) { float r; asm("v_exp_f32 %0, %1" : "=v"(r) : "v"(x)); return r; }
__device__ __forceinline__ f32x4 fzero4() { f32x4 z; z[0]=0.f; z[1]=0.f; z[2]=0.f; z[3]=0.f; return z; }
__device__ __forceinline__ b16x8 bzero8() {
  b16x8 z;
  #pragma unroll
  for (int j = 0; j < 8; ++j) z[j] = (__bf16)0.f;
  return z;
}
// barrier that drains only LDS (no vmcnt drain): loads/stores fly across
__device__ __forceinline__ void bar_lgkm() {
  asm volatile("s_waitcnt lgkmcnt(0)\n\ts_barrier" ::: "memory");
}

// ---------------- prep: weights -> bf16 (gate weights pre-scaled by log2e) ----------------
__global__ __launch_bounds__(256) void prep_kernel(
    const float* __restrict__ W1, const float* __restrict__ W2,
    const float* __restrict__ Wih, const float* __restrict__ Whh,
    const float* __restrict__ Wp, const float* __restrict__ Wv,
    const float* __restrict__ bih, const float* __restrict__ bhh,
    u16* __restrict__ W1b, u16* __restrict__ W2b, u16* __restrict__ Wihb,
    u16* __restrict__ Whhb, u16* __restrict__ Whb, float* __restrict__ gbp)
{
  int i = blockIdx.x * 256 + threadIdx.x;   // grid 256*256 = 65536
  if (i < 8192) {                            // W1 padded (128 x 64), K 54->64
    int r = i >> 6, k = i & 63;
    W1b[i] = f2bf_bits(k < 54 ? W1[r * 54 + k] : 0.f);
  }
  if (i < 16384) W2b[i] = f2bf_bits(W2[i]);  // 128x128
  Wihb[i] = f2bf_bits(LOG2E * Wih[i]);       // 512x128, pre-scaled
  Whhb[i] = f2bf_bits(LOG2E * Whh[i]);       // 512x128, pre-scaled
  if (i < 2048) {                            // head: rows 0-5 Wp, 6 Wv, 7-15 zero (16x128)
    int r = i >> 7, k = i & 127;
    float v = (r < 6) ? Wp[r * 128 + k] : ((r == 6) ? Wv[k] : 0.f);
    Whb[i] = f2bf_bits(v);                   // NOT scaled
  }
  if (i < 512) gbp[i] = LOG2E * (bih[i] + bhh[i]);
}

// ---------------- phase 1: X2 = relu(relu(obs@W1^T+b1)@W2^T+b2) as bf16 ----------------
__global__ __launch_bounds__(256) void mlp_kernel(
    const float* __restrict__ obs, const float* __restrict__ b1v, const float* __restrict__ b2v,
    const u16* __restrict__ W1b, const u16* __restrict__ W2b, u16* __restrict__ X2)
{
  __shared__ __align__(16) float obst[64 * 54];
  __shared__ u16 x1t[64 * 128];
  __shared__ u16 x2t[64 * 128];
  const int tid = threadIdx.x;
  const int w   = tid >> 6;
  const int l   = tid & 63;
  const int col = l & 15;
  const int q   = l >> 4;
  const long m0 = (long)blockIdx.x * 64;   // 4096 blocks * 64 rows = 262144 = T*N

  {
    const float* osrc = obs + m0 * 54;
    #pragma unroll
    for (int j = 0; j < 4; ++j) {
      int i4 = tid + 256 * j;
      if (i4 < 864) *(float4*)&obst[i4 * 4] = *(const float4*)&osrc[i4 * 4];
    }
  }
  __syncthreads();

  b16x8 a0[2];
  {
    const float* orow = obst + (16 * w + col) * 54;
    #pragma unroll
    for (int c = 0; c < 2; ++c) {
      #pragma unroll
      for (int p = 0; p < 4; ++p) {
        int k0 = 32 * c + 8 * q + 2 * p;
        float x0 = 0.f, x1 = 0.f;
        if (k0 < 54) { x0 = orow[k0]; x1 = orow[k0 + 1]; }
        a0[c][2 * p]     = (__bf16)x0;
        a0[c][2 * p + 1] = (__bf16)x1;
      }
    }
  }
  f32x4 acc[8];
  #pragma unroll
  for (int i = 0; i < 8; ++i) acc[i] = fzero4();
  #pragma unroll
  for (int nt = 0; nt < 8; ++nt) {
    #pragma unroll
    for (int c = 0; c < 2; ++c) {
      b16x8 b = *(const b16x8*)(W1b + (nt * 16 + col) * 64 + 8 * q + 32 * c);
      acc[nt] = MFMA16(a0[c], b, acc[nt]);
    }
  }
  #pragma unroll
  for (int nt = 0; nt < 8; ++nt) {
    float bb = b1v[nt * 16 + col];
    #pragma unroll
    for (int r = 0; r < 4; ++r) {
      float v = fmaxf(acc[nt][r] + bb, 0.f);
      int row = 16 * w + 4 * q + r;
      int byteoff = row * 256 + (nt * 16 + col) * 2;
      *(u16*)((char*)x1t + SW(byteoff, row)) = f2bf_bits(v);
    }
  }
  __syncthreads();

  b16x8 a1[4];
  #pragma unroll
  for (int c = 0; c < 4; ++c) {
    int row = 16 * w + col;
    int byteoff = row * 256 + 16 * q + 64 * c;
    a1[c] = *(const b16x8*)((char*)x1t + SW(byteoff, row));
  }
  f32x4 acc2[8];
  #pragma unroll
  for (int i = 0; i < 8; ++i) acc2[i] = fzero4();
  #pragma unroll
  for (int nt = 0; nt < 8; ++nt) {
    #pragma unroll
    for (int c = 0; c < 4; ++c) {
      b16x8 b = *(const b16x8*)(W2b + (nt * 16 + col) * 128 + 8 * q + 32 * c);
      acc2[nt] = MFMA16(a1[c], b, acc2[nt]);
    }
  }
  #pragma unroll
  for (int nt = 0; nt < 8; ++nt) {
    float bb = b2v[nt * 16 + col];
    #pragma unroll
    for (int r = 0; r < 4; ++r) {
      float v = fmaxf(acc2[nt][r] + bb, 0.f);
      int row = 16 * w + 4 * q + r;
      int byteoff = row * 256 + (nt * 16 + col) * 2;
      *(u16*)((char*)x2t + SW(byteoff, row)) = f2bf_bits(v);
    }
  }
  __syncthreads();

  #pragma unroll
  for (int i = 0; i < 4; ++i) {
    int e = tid + 256 * i;
    int byteoff = e * 16;
    int row = byteoff >> 8;
    uint4 v = *(const uint4*)((char*)x2t + SW(byteoff, row));
    *(uint4*)((char*)X2 + m0 * 256 + byteoff) = v;
  }
}

// ---------------- phase 2: LSTM recurrence + fused 2-step heads ----------------
// 256 blocks x 8 batch rows, 512 threads (8 waves); wave w owns gate cols [16w,16w+16)
__global__ __launch_bounds__(512) void lstm_kernel(
    const u16* __restrict__ X2, const float* __restrict__ h0, const float* __restrict__ c0,
    const int* __restrict__ done,
    const u16* __restrict__ Wihb, const u16* __restrict__ Whhb, const u16* __restrict__ Whb,
    const float* __restrict__ gb, const float* __restrict__ bp, const float* __restrict__ bv,
    float* __restrict__ out)
{
  __shared__ u16 hring[4][8 * 128];  // 4-deep ring of h tiles (swizzled)
  __shared__ int dsh[1024];          // done[t][0..7] staged
  const int tid = threadIdx.x;
  const int w   = tid >> 6;
  const int l   = tid & 63;
  const int col = l & 15;
  const int q   = l >> 4;
  const int cl  = col & 7;
  const int n0  = blockIdx.x * 8;    // 256 blocks * 8 rows = 2048
  // elementwise-spread row base: q0->0, q1->4, q2->2, q3->6 (each lane owns rows rbase, rbase+1)
  const int rbase = ((q & 1) << 2) + ((q >> 1) << 1);

  // resident gate-weight fragments (pre-scaled by log2e)
  b16x8 wih[4][4], whh[4][4];
  #pragma unroll
  for (int g = 0; g < 4; ++g) {
    int nt = 8 * g + w;
    #pragma unroll
    for (int c = 0; c < 4; ++c) {
      wih[g][c] = *(const b16x8*)(Wihb + (nt * 16 + col) * 128 + 8 * q + 32 * c);
      whh[g][c] = *(const b16x8*)(Whhb + (nt * 16 + col) * 128 + 8 * q + 32 * c);
    }
  }
  float gbr[4];
  #pragma unroll
  for (int g = 0; g < 4; ++g) gbr[g] = gb[(8 * g + w) * 16 + col];
  const float hb = (col < 6) ? bp[col] : ((col == 6) ? bv[0] : 0.f);

  // c-state: 2 cells per lane (rows rbase, rbase+1; hcol 16w+col)
  float cc0 = c0[(n0 + rbase) * 128 + 16 * w + col];
  float cc1 = c0[(n0 + rbase + 1) * 128 + 16 * w + col];

  // stage h0 -> hring[0]; done -> dsh
  #pragma unroll
  for (int j = 0; j < 2; ++j) {
    int idx = tid * 2 + j;           // 1024 = 8 rows * 128
    int row = idx >> 7, k = idx & 127;
    *(u16*)((char*)hring[0] + SW(row * 256 + k * 2, row)) = f2bf_bits(h0[(n0 + row) * 128 + k]);
    dsh[idx] = done[(idx >> 3) * 2048 + n0 + (idx & 7)];
  }
  __syncthreads();

  // loop-invariant LDS offsets
  int offr[4];
  #pragma unroll
  for (int c = 0; c < 4; ++c) offr[c] = SW(cl * 256 + 16 * q + 64 * c, cl);
  const int wcol2 = (16 * w + col) * 2;
  const int offw0 = SW(rbase * 256 + wcol2, rbase);
  const int offw1 = SW((rbase + 1) * 256 + wcol2, rbase + 1);

  // x2 fragment pointer (per-lane); t=0 preloaded, xp then points at t+1
  const u16* xp = X2 + (n0 + cl) * 128 + 8 * q;
  b16x8 xa[4];
  #pragma unroll
  for (int c = 0; c < 4; ++c) xa[c] = *(const b16x8*)(xp + 32 * c);
  xp += 262144;

  int dA = 0, dC0 = 0, dC1 = 0;
  float hv0 = 0.f, hv1 = 0.f;

  for (int tb = 0; tb < 128; tb += 4) {
    #pragma unroll
    for (int u = 0; u < 4; ++u) {
      const int t = tb + u;
      const u16* rbuf = hring[u];
      u16* wbuf = hring[(u + 1) & 3];

      // fused head for pair (t-2, t-1), rotated across waves (reads slots (u+3)&3 and u)
      if (((t & 1) == 0) && (t >= 2) && (w == (((t - 2) >> 1) & 7))) {
        const u16* bufA = hring[(u + 3) & 3];   // h_{t-2}
        const char* hbase = (const char*)((col < 8) ? bufA : rbuf);
        f32x4 hacc = fzero4();
        #pragma unroll
        for (int c = 0; c < 4; ++c) {
          b16x8 hh = *(const b16x8*)(hbase + offr[c]);
          b16x8 wf = *(const b16x8*)(Whb + col * 128 + 8 * q + 32 * c);
          hacc = MFMA16(hh, wf, hacc);
        }
        #pragma unroll
        for (int r = 0; r < 4; ++r) {
          int m = 4 * q + r;
          int tt = (t - 2) + (m >> 3);
          int n = n0 + (m & 7);
          float v = hacc[r] + hb;
          if (col < 6)       out[(tt * 2048 + n) * 6 + col] = v;
          else if (col == 6) out[1572864 + tt * 2048 + n] = v;
        }
      }

      // h_{t-1} fragments; zero rows where episode ended at t-1
      b16x8 ha[4];
      #pragma unroll
      for (int c = 0; c < 4; ++c) {
        ha[c] = *(const b16x8*)((const char*)rbuf + offr[c]);
        if (dA) ha[c] = bzero8();
      }
      if (dC0) cc0 = 0.f;
      if (dC1) cc1 = 0.f;

      // prefetch next step's x fragments (flies across barriers; no vmcnt drain)
      b16x8 xn[4];
      #pragma unroll
      for (int c = 0; c < 4; ++c) xn[c] = *(const b16x8*)(xp + 32 * c);

      f32x4 acc[4];
      #pragma unroll
      for (int g = 0; g < 4; ++g) acc[g] = fzero4();
      #pragma unroll
      for (int g = 0; g < 4; ++g)
        #pragma unroll
        for (int c = 0; c < 4; ++c)
          acc[g] = MFMA16(xa[c], wih[g][c], acc[g]);
      #pragma unroll
      for (int g = 0; g < 4; ++g)
        #pragma unroll
        for (int c = 0; c < 4; ++c)
          acc[g] = MFMA16(ha[c], whh[g][c], acc[g]);

      // masks for next step (done[t])
      dA  = dsh[t * 8 + cl];
      dC0 = dsh[t * 8 + rbase];
      dC1 = dsh[t * 8 + rbase + 1];

      // spread cells across all lanes: q2/q3 take partner's acc rows 2,3
      #pragma unroll
      for (int g = 0; g < 4; ++g) {
        asm volatile("v_permlane32_swap_b32 %0, %1" : "+v"(acc[g][0]), "+v"(acc[g][2]));
        asm volatile("v_permlane32_swap_b32 %0, %1" : "+v"(acc[g][1]), "+v"(acc[g][3]));
      }

      // elementwise LSTM cell, 2 cells/lane (gates pre-scaled by log2e)
      {
        float gi = acc[0][0] + gbr[0], gf = acc[1][0] + gbr[1];
        float gg = acc[2][0] + gbr[2], go = acc[3][0] + gbr[3];
        float si = rcp_f(1.f + exp2_f(-gi));
        float sf = rcp_f(1.f + exp2_f(-gf));
        float tg = 1.f - 2.f * rcp_f(1.f + exp2_f(gg + gg));
        float cn = sf * cc0 + si * tg;
        float so = rcp_f(1.f + exp2_f(-go));
        float tc = 1.f - 2.f * rcp_f(1.f + exp2_f(2.8853900817779268f * cn));
        cc0 = cn; hv0 = so * tc;
      }
      {
        float gi = acc[0][1] + gbr[0], gf = acc[1][1] + gbr[1];
        float gg = acc[2][1] + gbr[2], go = acc[3][1] + gbr[3];
        float si = rcp_f(1.f + exp2_f(-gi));
        float sf = rcp_f(1.f + exp2_f(-gf));
        float tg = 1.f - 2.f * rcp_f(1.f + exp2_f(gg + gg));
        float cn = sf * cc1 + si * tg;
        float so = rcp_f(1.f + exp2_f(-go));
        float tc = 1.f - 2.f * rcp_f(1.f + exp2_f(2.8853900817779268f * cn));
        cc1 = cn; hv1 = so * tc;
      }

      // pack h -> bf16, write to ring slot (u+1)&3
      {
        u32 pk;
        asm("v_cvt_pk_bf16_f32 %0, %1, %2" : "=v"(pk) : "v"(hv0), "v"(hv1));
        *(u16*)((char*)wbuf + offw0) = (u16)pk;
        *(u16*)((char*)wbuf + offw1) = (u16)(pk >> 16);
      }
      bar_lgkm();   // LDS-only drain; global loads/stores stay in flight

      #pragma unroll
      for (int c = 0; c < 4; ++c) xa[c] = xn[c];
      xp += 262144;
    }
  }

  // final head pair (126,127): h126 in slot 3, h127 in slot 0
  if (w == 7) {
    const char* hbase = (const char*)((col < 8) ? hring[3] : hring[0]);
    f32x4 hacc = fzero4();
    #pragma unroll
    for (int c = 0; c < 4; ++c) {
      b16x8 hh = *(const b16x8*)(hbase + offr[c]);
      b16x8 wf = *(const b16x8*)(Whb + col * 128 + 8 * q + 32 * c);
      hacc = MFMA16(hh, wf, hacc);
    }
    #pragma unroll
    for (int r = 0; r < 4; ++r) {
      int m = 4 * q + r;
      int tt = 126 + (m >> 3);
      int n = n0 + (m & 7);
      float v = hacc[r] + hb;
      if (col < 6)       out[(tt * 2048 + n) * 6 + col] = v;
      else if (col == 6) out[1572864 + tt * 2048 + n] = v;
    }
  }

  // final hT / cT (f32), 2 rows per lane
  {
    int k = 16 * w + col;
    out[1835008 + (n0 + rbase) * 128 + k]     = hv0;
    out[1835008 + (n0 + rbase + 1) * 128 + k] = hv1;
    out[2097152 + (n0 + rbase) * 128 + k]     = cc0;
    out[2097152 + (n0 + rbase + 1) * 128 + k] = cc1;
  }
}

extern "C" void kernel_launch(void* const* d_in, const int* in_sizes, int n_in,
                              void* d_out, int out_size, void* d_ws, size_t ws_size,
                              hipStream_t stream) {
  const float* obs  = (const float*)d_in[0];
  const float* h0   = (const float*)d_in[1];
  const float* c0   = (const float*)d_in[2];
  const int*   done = (const int*)d_in[3];
  const float* W1   = (const float*)d_in[4];
  const float* b1   = (const float*)d_in[5];
  const float* W2   = (const float*)d_in[6];
  const float* b2   = (const float*)d_in[7];
  const float* Wih  = (const float*)d_in[8];
  const float* Whh  = (const float*)d_in[9];
  const float* bih  = (const float*)d_in[10];
  const float* bhh  = (const float*)d_in[11];
  const float* Wp   = (const float*)d_in[12];
  const float* bp   = (const float*)d_in[13];
  const float* Wv   = (const float*)d_in[14];
  const float* bv   = (const float*)d_in[15];

  char* ws = (char*)d_ws;
  u16*   X2   = (u16*)(ws);                                      // 67108864 B
  u16*   W1b  = (u16*)(ws + 67108864);                           // 16384 B
  u16*   W2b  = (u16*)(ws + 67108864 + 16384);                   // 32768 B
  u16*   Wihb = (u16*)(ws + 67108864 + 16384 + 32768);           // 131072 B
  u16*   Whhb = (u16*)(ws + 67108864 + 16384 + 32768 + 131072);  // 131072 B
  u16*   Whb  = (u16*)(ws + 67108864 + 16384 + 32768 + 262144);  // 4096 B
  float* gbp  = (float*)(ws + 67108864 + 16384 + 32768 + 262144 + 4096);
  float* out  = (float*)d_out;

  hipLaunchKernelGGL(prep_kernel, dim3(256), dim3(256), 0, stream,
                     W1, W2, Wih, Whh, Wp, Wv, bih, bhh, W1b, W2b, Wihb, Whhb, Whb, gbp);
  hipLaunchKernelGGL(mlp_kernel, dim3(4096), dim3(256), 0, stream,
                     obs, b1, b2, W1b, W2b, X2);
  hipLaunchKernelGGL(lstm_kernel, dim3(256), dim3(512), 0, stream,
                     X2, h0, c0, done, Wihb, Whhb, Whb, gbp, bp, bv, out);
}